// Round 5
// baseline (221.792 us; speedup 1.0000x reference)
//
#include <hip/hip_runtime.h>
#include <hip/hip_bf16.h>
#include <math.h>

#define LSEQ 32768
#define DMODEL 256
#define DHID 256
#define NCH 512                 // interleaved [re,im] hidden channels: col 2h=re, 2h+1=im
#define CHUNK 128
#define NCHUNKS (LSEQ / CHUNK)  // 256

typedef __bf16 bf16_t;
typedef _Float16 f16_t;
typedef __bf16 bf16x8 __attribute__((ext_vector_type(8)));
typedef float f32x4 __attribute__((ext_vector_type(4)));

__device__ __forceinline__ void async_load16(const void* g, void* l) {
  __builtin_amdgcn_global_load_lds((__attribute__((address_space(1))) void*)g,
                                   (__attribute__((address_space(3))) void*)l,
                                   16, 0, 0);
}

__device__ __forceinline__ float f16tof(unsigned int u) {
  return (float)__builtin_bit_cast(_Float16, (unsigned short)(u & 0xffffu));
}
__device__ __forceinline__ unsigned int fTobf(float f) {
  return (unsigned int)__builtin_bit_cast(unsigned short, (bf16_t)f);
}

// ---- prep: params + zero flags + W1 + W2, one launch ------------------------
// lam rows: 0,1 = lambda; 2,3 = lambda^64; 4+2j,5+2j (j=0..7) = lambda^(128*2^j)
__global__ void prep_all(const float* __restrict__ nu_log,
                         const float* __restrict__ theta_log,
                         const float* __restrict__ gamma_log,
                         const float* __restrict__ B_re, const float* __restrict__ B_im,
                         const float* __restrict__ C_re, const float* __restrict__ C_im,
                         float* __restrict__ lam, bf16_t* __restrict__ W1,
                         bf16_t* __restrict__ W2, int* __restrict__ flags) {
  const int bid = blockIdx.x, tid = threadIdx.x;
  if (bid == 0) {
    int h = tid;
    if (h < DHID) {
      double nu = exp((double)nu_log[h]);
      double th = exp((double)theta_log[h]);
#define PUT(row, n) { \
      double mag = exp(-(double)(n) * nu); \
      double ph  = fmod((double)(n) * th, 6.283185307179586); \
      lam[(row) * DHID + h]     = (float)(mag * cos(ph)); \
      lam[((row)+1) * DHID + h] = (float)(mag * sin(ph)); }
      PUT(0, 1.0)
      PUT(2, 64.0)
      for (int j = 0; j < 8; ++j) PUT(4 + 2 * j, 128.0 * (double)(1 << j))
#undef PUT
    }
  } else if (bid == 1) {
    if (tid < NCHUNKS) flags[tid] = 0;
  } else if (bid < 514) {
    // W1[n][k], n interleaved: n=2h -> B_re[h][k]*g; n=2h+1 -> B_im[h][k]*g
    int n = bid - 2, k = tid, h = n >> 1;
    float g = expf(gamma_log[h]);
    float v = (((n & 1) == 0) ? B_re[h * DMODEL + k] : B_im[h * DMODEL + k]) * g;
    W1[n * DMODEL + k] = (bf16_t)v;
  } else {
    // W2[m][k], k interleaved: k=2h -> C_re[m][h]; k=2h+1 -> -C_im[m][h]
    int idx = bid - 514;
    int m = idx >> 1, k = (idx & 1) * 256 + tid, h = k >> 1;
    float v = ((k & 1) == 0) ? C_re[m * DHID + h] : -C_im[m * DHID + h];
    W2[m * NCH + k] = (bf16_t)v;
  }
}

// ---- single fused kernel, decoupled lookback, H never leaves LDS -----------
// 256 blocks (1/CU, 144 KB LDS), 512 threads. Per block (chunk c):
//   A: GEMM1 128x512 K=256 (A from f32 inputs, reg-converted; W1 via DMA)
//   B: acc -> H fp16 swizzled (128 KB LDS)
//   C: local end state E_c (2 segs x 64 + lambda^64 combine) -> publish+flag
//   D: thread-parallel flag poll -> lambda^128 Horner lookback over E[0..c-1]
//   E: in-place carry scan of H (fp16 -> bf16)
//   F: GEMM2 out = H @ W2^T + X*D
__global__ __launch_bounds__(512) void lru_fused(
    const float* __restrict__ X, const bf16_t* __restrict__ W1,
    const bf16_t* __restrict__ W2, const float* __restrict__ lam,
    float* __restrict__ E, int* __restrict__ flags,
    const float* __restrict__ Dv, float* __restrict__ out) {
  __shared__ __align__(16) char smem[147456];   // 144 KB
  char*   H   = smem;                           // [128][1024B] swizzled pairs
  bf16_t* As  = (bf16_t*)smem;                  // [128][32] 8 KB  (GEMM1, aliases H)
  bf16_t* Ws1 = (bf16_t*)(smem + 8192);         // [512][32] 32 KB (GEMM1, aliases H)
  bf16_t* Bs2 = (bf16_t*)(smem + 131072);       // [256][32] 16 KB (GEMM2 staging)
  float*  Ep  = (float*)(smem + 131072);        // aliases Bs2; used pre-GEMM2 only

  const int tid = threadIdx.x;
  const int c = blockIdx.x;
  const int r0 = c * CHUNK;
  const int wave = tid >> 6, lane = tid & 63;
  const int wm = wave & 1, wn = wave >> 1;
  const int lrow = lane & 15, lk = lane >> 4;
  const int ra = tid >> 2, ka = (tid & 3) * 8;

  // ---------------- Phase A: GEMM1, 128(t) x 512(ch), K=256 ------------------
  f32x4 acc[4][8] = {};
  for (int k0 = 0; k0 < DMODEL; k0 += 32) {
    // A loads issued early (overlap previous MFMA); f32 -> bf16 in regs
    const float* xrow = X + (size_t)(r0 + ra) * DMODEL + k0 + ka;
    float4 a0 = ((const float4*)xrow)[0];
    float4 a1 = ((const float4*)xrow)[1];
    __syncthreads();  // previous iteration's frag reads done
#pragma unroll
    for (int it = 0; it < 4; ++it) {
      int idx = it * 512 + tid;
      async_load16(W1 + (size_t)(idx >> 2) * DMODEL + k0 + (idx & 3) * 8,
                   (char*)Ws1 + idx * 16);
    }
    bf16x8 av = {(bf16_t)a0.x, (bf16_t)a0.y, (bf16_t)a0.z, (bf16_t)a0.w,
                 (bf16_t)a1.x, (bf16_t)a1.y, (bf16_t)a1.z, (bf16_t)a1.w};
    *(bf16x8*)(As + ra * 32 + ka) = av;
    __syncthreads();
    bf16x8 af[4], bfr[8];
#pragma unroll
    for (int i = 0; i < 4; ++i)
      af[i] = *(const bf16x8*)(As + (wm * 64 + i * 16 + lrow) * 32 + lk * 8);
#pragma unroll
    for (int j = 0; j < 8; ++j)
      bfr[j] = *(const bf16x8*)(Ws1 + (wn * 128 + j * 16 + lrow) * 32 + lk * 8);
#pragma unroll
    for (int i = 0; i < 4; ++i)
#pragma unroll
      for (int j = 0; j < 8; ++j)
        acc[i][j] = __builtin_amdgcn_mfma_f32_16x16x32_bf16(af[i], bfr[j], acc[i][j], 0, 0, 0);
  }
  __syncthreads();  // frag reads done; As/Ws1 region becomes H

  // ---------------- Phase B: acc -> H (fp16 pairs, swizzled) -----------------
#pragma unroll
  for (int i = 0; i < 4; ++i)
#pragma unroll
    for (int r = 0; r < 4; ++r) {
      int row = wm * 64 + i * 16 + lk * 4 + r;
      int key = (row & 7) << 4;
#pragma unroll
      for (int j = 0; j < 8; ++j) {
        int col = wn * 128 + j * 16 + lrow;
        *(f16_t*)(H + row * 1024 + ((col * 2) ^ key)) = (f16_t)acc[i][j][r];
      }
    }
  __syncthreads();

  // ---------------- Phase C: local E_c (2 segs x 64 rows + lambda^64) --------
  {
    int p = tid & 255, seg = tid >> 8;
    float lre = lam[p], lim = lam[DHID + p];
    float sre = 0.f, sim = 0.f;
    int cb = 4 * p;
#pragma unroll 4
    for (int t = 0; t < 64; ++t) {
      int row = seg * 64 + t;
      unsigned int w = *(const unsigned int*)(H + row * 1024 + (cb ^ ((row & 7) << 4)));
      float bre = f16tof(w), bim = f16tof(w >> 16);
      float nre = fmaf(lre, sre, fmaf(-lim, sim, bre));
      float nim = fmaf(lre, sim, fmaf(lim, sre, bim));
      sre = nre; sim = nim;
    }
    Ep[seg * 512 + 2 * p]     = sre;
    Ep[seg * 512 + 2 * p + 1] = sim;
  }
  __syncthreads();
  if (tid < 256) {
    int p = tid;
    float ar = lam[2 * DHID + p], ai = lam[3 * DHID + p];  // lambda^64
    float s0r = Ep[2 * p], s0i = Ep[2 * p + 1];
    float s1r = Ep[512 + 2 * p], s1i = Ep[512 + 2 * p + 1];
    float er = fmaf(ar, s0r, fmaf(-ai, s0i, s1r));
    float ei = fmaf(ar, s0i, fmaf(ai, s0r, s1i));
    float2 ev = {er, ei};
    *(float2*)(E + (size_t)c * NCH + 2 * p) = ev;
  }
  __threadfence();          // device-scope: E visible before flag
  __syncthreads();
  if (tid == 0)
    __hip_atomic_store(&flags[c], 1, __ATOMIC_RELEASE, __HIP_MEMORY_SCOPE_AGENT);

  // ---------------- Phase D: poll predecessors, Horner lookback --------------
  if (c > 0) {
    int got = (tid < c) ? 0 : 1;  // thread k polls flag[k]
    for (;;) {
      if (!got)
        got = (__hip_atomic_load(&flags[tid], __ATOMIC_RELAXED,
                                 __HIP_MEMORY_SCOPE_AGENT) != 0);
      if (__syncthreads_and(got)) break;
    }
    __threadfence();        // acquire: E reads below see producers' data
  }
  {
    int p = tid & 255, half = tid >> 8;
    int m = c >> 1;
    int lo = half ? m : 0, end = half ? c : m;
    float aR = lam[4 * DHID + p], aI = lam[5 * DHID + p];  // lambda^128
    float sr = 0.f, si = 0.f;
#pragma unroll 4
    for (int k = lo; k < end; ++k) {
      float2 e = *(const float2*)(E + (size_t)k * NCH + 2 * p);
      float nr = fmaf(aR, sr, fmaf(-aI, si, e.x));
      float ni = fmaf(aR, si, fmaf(aI, sr, e.y));
      sr = nr; si = ni;
    }
    Ep[half * 512 + 2 * p]     = sr;
    Ep[half * 512 + 2 * p + 1] = si;
  }
  __syncthreads();

  // ---------------- Phase E: carry combine + in-place scan of H --------------
  if (tid < 256) {
    int p = tid;
    int lenb = c - (c >> 1);
    float pr = 1.f, pi = 0.f;  // lambda^(128*lenb) via fp64-accurate bit table
#pragma unroll
    for (int j = 0; j < 8; ++j)
      if (lenb & (1 << j)) {
        float br = lam[(4 + 2 * j) * DHID + p], bi = lam[(5 + 2 * j) * DHID + p];
        float nr = pr * br - pi * bi, ni = pr * bi + pi * br;
        pr = nr; pi = ni;
      }
    float sar = Ep[2 * p], sai = Ep[2 * p + 1];
    float sbr = Ep[512 + 2 * p], sbi = Ep[512 + 2 * p + 1];
    float carR = fmaf(pr, sar, fmaf(-pi, sai, sbr));
    float carI = fmaf(pr, sai, fmaf(pi, sar, sbi));

    float lre = lam[p], lim = lam[DHID + p];
    float sre = carR, sim = carI;
    int cb = 4 * p;
#pragma unroll 4
    for (int t = 0; t < CHUNK; ++t) {
      unsigned int* ptr = (unsigned int*)(H + t * 1024 + (cb ^ ((t & 7) << 4)));
      unsigned int w = *ptr;
      float bre = f16tof(w), bim = f16tof(w >> 16);
      float nre = fmaf(lre, sre, fmaf(-lim, sim, bre));
      float nim = fmaf(lre, sim, fmaf(lim, sre, bim));
      sre = nre; sim = nim;
      *ptr = (fTobf(sim) << 16) | fTobf(sre);
    }
  }

  // ---------------- Phase F: GEMM2 out = H @ W2^T + X*D ----------------------
  f32x4 acc2[4][4] = {};
  for (int k0 = 0; k0 < NCH; k0 += 32) {
    __syncthreads();  // first iter: scan + Ep reads done before Bs2 overwrite
#pragma unroll
    for (int it = 0; it < 2; ++it) {
      int idx = it * 512 + tid;
      async_load16(W2 + (size_t)(idx >> 2) * NCH + k0 + (idx & 3) * 8,
                   (char*)Bs2 + idx * 16);
    }
    __syncthreads();
    bf16x8 af2[4], bf2[4];
#pragma unroll
    for (int i = 0; i < 4; ++i) {
      int m = wm * 64 + i * 16 + lrow;
      af2[i] = *(const bf16x8*)(H + m * 1024 + ((2 * k0 + lk * 16) ^ ((m & 7) << 4)));
    }
#pragma unroll
    for (int j = 0; j < 4; ++j)
      bf2[j] = *(const bf16x8*)(Bs2 + (wn * 64 + j * 16 + lrow) * 32 + lk * 8);
#pragma unroll
    for (int i = 0; i < 4; ++i)
#pragma unroll
      for (int j = 0; j < 4; ++j)
        acc2[i][j] = __builtin_amdgcn_mfma_f32_16x16x32_bf16(af2[i], bf2[j], acc2[i][j], 0, 0, 0);
  }

#pragma unroll
  for (int i = 0; i < 4; ++i)
#pragma unroll
    for (int r = 0; r < 4; ++r) {
      int row = r0 + wm * 64 + i * 16 + lk * 4 + r;
#pragma unroll
      for (int j = 0; j < 4; ++j) {
        int col = wn * 64 + j * 16 + lrow;
        float v = acc2[i][j][r] + X[(size_t)row * DMODEL + col] * Dv[col];
        out[(size_t)row * DMODEL + col] = v;
      }
    }
}

extern "C" void kernel_launch(void* const* d_in, const int* in_sizes, int n_in,
                              void* d_out, int out_size, void* d_ws, size_t ws_size,
                              hipStream_t stream) {
  const float* inputs    = (const float*)d_in[0];
  const float* nu_log    = (const float*)d_in[1];
  const float* theta_log = (const float*)d_in[2];
  const float* gamma_log = (const float*)d_in[3];
  const float* B_re      = (const float*)d_in[4];
  const float* B_im      = (const float*)d_in[5];
  const float* C_re      = (const float*)d_in[6];
  const float* C_im      = (const float*)d_in[7];
  const float* Dvec      = (const float*)d_in[8];
  float* out = (float*)d_out;

  char* w = (char*)d_ws;
  bf16_t* W1 = (bf16_t*)w; w += (size_t)NCH * DMODEL * 2;   // 256 KB
  bf16_t* W2 = (bf16_t*)w; w += (size_t)DMODEL * NCH * 2;   // 256 KB
  float* lam = (float*)w;  w += 24576;                      // 20 rows used
  float* E   = (float*)w;  w += (size_t)NCHUNKS * NCH * 4;  // 512 KB
  int* flags = (int*)w;    w += 4096;                       // 1 KB used

  // grid: 1 (params) + 1 (flag zero) + 512 (W1) + 512 (W2) = 1026
  prep_all<<<1026, 256, 0, stream>>>(nu_log, theta_log, gamma_log,
                                     B_re, B_im, C_re, C_im,
                                     lam, W1, W2, flags);
  lru_fused<<<NCHUNKS, 512, 0, stream>>>(inputs, W1, W2, lam, E, flags,
                                         Dvec, out);
}

// Round 6
// 155.328 us; speedup vs baseline: 1.4279x; 1.4279x over previous
//
#include <hip/hip_runtime.h>
#include <hip/hip_bf16.h>
#include <math.h>

#define LSEQ 32768
#define DMODEL 256
#define DHID 256
#define NCH 512                 // interleaved [re,im] hidden channels: col 2h=re, 2h+1=im
#define CHUNK 128
#define NCHUNKS (LSEQ / CHUNK)  // 256

typedef __bf16 bf16_t;
typedef _Float16 f16_t;
typedef __bf16 bf16x8 __attribute__((ext_vector_type(8)));
typedef float f32x4 __attribute__((ext_vector_type(4)));

__device__ __forceinline__ void async_load16(const void* g, void* l) {
  __builtin_amdgcn_global_load_lds((__attribute__((address_space(1))) void*)g,
                                   (__attribute__((address_space(3))) void*)l,
                                   16, 0, 0);
}

__device__ __forceinline__ float f16tof(unsigned int u) {
  return (float)__builtin_bit_cast(_Float16, (unsigned short)(u & 0xffffu));
}
__device__ __forceinline__ unsigned int fTobf(float f) {
  return (unsigned int)__builtin_bit_cast(unsigned short, (bf16_t)f);
}

// ---- prep: params + W1 + W2, one launch -------------------------------------
// lam rows: 0,1 = lambda; 2,3 = lambda^32; 4+2j,5+2j (j=0..7) = lambda^(128*2^j)
__global__ void prep_all(const float* __restrict__ nu_log,
                         const float* __restrict__ theta_log,
                         const float* __restrict__ gamma_log,
                         const float* __restrict__ B_re, const float* __restrict__ B_im,
                         const float* __restrict__ C_re, const float* __restrict__ C_im,
                         float* __restrict__ lam, bf16_t* __restrict__ W1,
                         bf16_t* __restrict__ W2) {
  const int bid = blockIdx.x, tid = threadIdx.x;
  if (bid == 0) {
    int h = tid;
    if (h < DHID) {
      double nu = exp((double)nu_log[h]);
      double th = exp((double)theta_log[h]);
#define PUT(row, n) { \
      double mag = exp(-(double)(n) * nu); \
      double ph  = fmod((double)(n) * th, 6.283185307179586); \
      lam[(row) * DHID + h]     = (float)(mag * cos(ph)); \
      lam[((row)+1) * DHID + h] = (float)(mag * sin(ph)); }
      PUT(0, 1.0)
      PUT(2, 32.0)
      for (int j = 0; j < 8; ++j) PUT(4 + 2 * j, 128.0 * (double)(1 << j))
#undef PUT
    }
  } else if (bid < 513) {
    // W1[n][k], n interleaved: n=2h -> B_re[h][k]*g; n=2h+1 -> B_im[h][k]*g
    int n = bid - 1, k = tid, h = n >> 1;
    float g = expf(gamma_log[h]);
    float v = (((n & 1) == 0) ? B_re[h * DMODEL + k] : B_im[h * DMODEL + k]) * g;
    W1[n * DMODEL + k] = (bf16_t)v;
  } else {
    // W2[m][k], k interleaved: k=2h -> C_re[m][h]; k=2h+1 -> -C_im[m][h]
    int idx = bid - 513;
    int m = idx >> 1, k = (idx & 1) * 256 + tid, h = k >> 1;
    float v = ((k & 1) == 0) ? C_re[m * DHID + h] : -C_im[m * DHID + h];
    W2[m * NCH + k] = (bf16_t)v;
  }
}

// ---------------- kernel A: GEMM1 (chunk tile) + fp16 Bu store + chunk E ----
// grid (2, NCHUNKS), 512 threads. Tile 128(t) x 256(ch), K=256. 68 KB LDS.
// A read directly from f32 inputs, converted to bf16 in regs (no xb pass).
// Bu global layout: [L][1024B] fp16, byte cb stored at cb ^ ((t&7)<<4).
// E[c][512]: interleaved (re,im) pairs, per-128-row chunk end state.
__global__ __launch_bounds__(512) void gemm1_scan(
    const float* __restrict__ X, const bf16_t* __restrict__ Bw,
    f16_t* __restrict__ Bu, const float* __restrict__ lam,
    float* __restrict__ E) {
  __shared__ __align__(16) char smem[69632];  // 68 KB
  bf16_t* As = (bf16_t*)smem;                 // [128][32] bf16 = 8 KB
  bf16_t* Bs = (bf16_t*)(smem + 8192);        // [256][32] bf16 = 16 KB
  char*   Bt = smem;                          // [128][512B] fp16 swizzled (aliases As/Bs)
  float*  Ep = (float*)(smem + 65536);        // [4][128][2] f32 = 4 KB

  const int tid = threadIdx.x;
  const int gx = blockIdx.x;          // channel half: pairs [gx*128, gx*128+128)
  const int c  = blockIdx.y;          // chunk
  const int r0 = c * CHUNK;
  const int c0 = gx * 256;            // column offset into the 512-wide Bu
  const int wave = tid >> 6, lane = tid & 63;
  const int wm = wave & 1, wn = wave >> 1;
  const int lrow = lane & 15, lk = lane >> 4;
  const int ra = tid >> 2, ka = (tid & 3) * 8;

  f32x4 acc[4][4] = {};

  for (int k0 = 0; k0 < DMODEL; k0 += 32) {
    // A loads issued early (f32 -> regs, overlap previous MFMA)
    const float* xrow = X + (size_t)(r0 + ra) * DMODEL + k0 + ka;
    float4 a0 = ((const float4*)xrow)[0];
    float4 a1 = ((const float4*)xrow)[1];
    __syncthreads();  // previous iteration's frag reads done
    async_load16(Bw + (size_t)(c0 + ra) * DMODEL + k0 + ka, (char*)Bs + tid * 16);
    async_load16(Bw + (size_t)(c0 + 128 + ra) * DMODEL + k0 + ka,
                 (char*)Bs + 8192 + tid * 16);
    bf16x8 av = {(bf16_t)a0.x, (bf16_t)a0.y, (bf16_t)a0.z, (bf16_t)a0.w,
                 (bf16_t)a1.x, (bf16_t)a1.y, (bf16_t)a1.z, (bf16_t)a1.w};
    *(bf16x8*)(As + ra * 32 + ka) = av;
    __syncthreads();
    bf16x8 af[4], bfr[4];
#pragma unroll
    for (int i = 0; i < 4; ++i)
      af[i] = *(const bf16x8*)(As + (wm * 64 + i * 16 + lrow) * 32 + lk * 8);
#pragma unroll
    for (int j = 0; j < 4; ++j)
      bfr[j] = *(const bf16x8*)(Bs + (wn * 64 + j * 16 + lrow) * 32 + lk * 8);
#pragma unroll
    for (int i = 0; i < 4; ++i)
#pragma unroll
      for (int j = 0; j < 4; ++j)
        acc[i][j] = __builtin_amdgcn_mfma_f32_16x16x32_bf16(af[i], bfr[j], acc[i][j], 0, 0, 0);
  }
  __syncthreads();  // all frag reads done before overwriting As/Bs with Bt

  // acc -> Bt (fp16, swizzled local half-rows of 512B)
#pragma unroll
  for (int i = 0; i < 4; ++i)
#pragma unroll
    for (int r = 0; r < 4; ++r) {
      int row = wm * 64 + i * 16 + lk * 4 + r;
      int key = (row & 7) << 4;
#pragma unroll
      for (int j = 0; j < 4; ++j) {
        int col = wn * 64 + j * 16 + lrow;
        *(f16_t*)(Bt + row * 512 + ((col * 2) ^ key)) = (f16_t)acc[i][j][r];
      }
    }
  __syncthreads();

  // Bt -> global Bu (byte-identical image; (r0+row)&7 == row&7 since r0%128==0)
  char* dst = (char*)Bu + (size_t)r0 * 1024 + gx * 512;
#pragma unroll
  for (int it = 0; it < 8; ++it) {
    int idx = it * 512 + tid;
    int row = idx >> 5, off = (idx & 31) * 16;
    *(f32x4*)(dst + (size_t)row * 1024 + off) = *(const f32x4*)(Bt + row * 512 + off);
  }

  // local end-states: 4 time segments of 32 rows per channel pair
  {
    int p = tid & 127, seg = tid >> 7;
    int h = gx * 128 + p;
    float lre = lam[h], lim = lam[DHID + h];
    float sre = 0.f, sim = 0.f;
    int cb = 4 * p;
#pragma unroll 4
    for (int t = 0; t < 32; ++t) {
      int row = seg * 32 + t;
      unsigned int w = *(const unsigned int*)(Bt + row * 512 + (cb ^ ((row & 7) << 4)));
      float bre = f16tof(w), bim = f16tof(w >> 16);
      float nre = fmaf(lre, sre, fmaf(-lim, sim, bre));
      float nim = fmaf(lre, sim, fmaf(lim, sre, bim));
      sre = nre; sim = nim;
    }
    Ep[seg * 256 + 2 * p]     = sre;
    Ep[seg * 256 + 2 * p + 1] = sim;
  }
  __syncthreads();
  // Horner combine of 4 segments with lambda^32 -> chunk end state E_c
  if (tid < 128) {
    int p = tid, h = gx * 128 + p;
    float ar = lam[2 * DHID + h], ai = lam[3 * DHID + h];  // lambda^32
    float er = Ep[2 * p], ei = Ep[2 * p + 1];
#pragma unroll
    for (int s = 1; s < 4; ++s) {
      float tr = fmaf(ar, er, fmaf(-ai, ei, Ep[s * 256 + 2 * p]));
      float ti = fmaf(ar, ei, fmaf(ai, er, Ep[s * 256 + 2 * p + 1]));
      er = tr; ei = ti;
    }
    E[(size_t)c * NCH + 2 * h]     = er;
    E[(size_t)c * NCH + 2 * h + 1] = ei;
  }
}

// ---------------- kernel B: stage chunk H -> lookback -> parallel scan -> GEMM2
// grid NCHUNKS, 1024 threads (16 waves), 152 KB LDS. Lookback over E[0..c-1]
// overlapped with the 128 KB H DMA. Scan parallelized 4x via 32-row segment
// partials + lambda^32 Horner start states (same decomposition gemm1 uses for E).
__global__ __launch_bounds__(1024) void scan_gemm2(
    const f16_t* __restrict__ Bu, const bf16_t* __restrict__ W2,
    const float* __restrict__ lam, const float* __restrict__ E,
    const float* __restrict__ X, const float* __restrict__ Dv,
    float* __restrict__ out) {
  __shared__ __align__(16) char smem[155648];
  char*   H  = smem;                          // [128][1024B] swizzled pairs
  bf16_t* Bs = (bf16_t*)(smem + 131072);      // [256][32] 16 KB (GEMM staging)
  float*  LB = (float*)(smem + 131072);       // [2][256][2] 4 KB (aliases Bs, pre-GEMM)
  float*  Pp = (float*)(smem + 135168);       // [4][256][2] 8 KB (aliases Bs, pre-GEMM)
  float*  Tt = (float*)(smem + 147456);       // [4][256][2] 8 KB (no alias)

  const int tid = threadIdx.x;
  const int c = (int)gridDim.x - 1 - (int)blockIdx.x;  // tail-first
  const int r0 = c * CHUNK;

  // issue 128 KB H staging (linear; global image == swizzled LDS image)
  const char* src = (const char*)Bu + (size_t)r0 * 1024;
#pragma unroll
  for (int it = 0; it < 8; ++it)
    async_load16(src + it * 16384 + tid * 16, H + it * 16384 + tid * 16);

  // lookback partials over E[0..c-1] (threads < 512; overlapped with DMA)
  if (tid < 512) {
    int p = tid & 255, half = tid >> 8;
    int m = c >> 1;
    int lo = half ? m : 0, end = half ? c : m;
    float aR = lam[4 * DHID + p], aI = lam[5 * DHID + p];  // lambda^128
    float sr = 0.f, si = 0.f;
#pragma unroll 4
    for (int k = lo; k < end; ++k) {
      float2 e = *(const float2*)(E + (size_t)k * NCH + 2 * p);
      float nr = fmaf(aR, sr, fmaf(-aI, si, e.x));
      float ni = fmaf(aR, si, fmaf(aI, sr, e.y));
      sr = nr; si = ni;
    }
    LB[half * 512 + 2 * p]     = sr;
    LB[half * 512 + 2 * p + 1] = si;
  }
  __syncthreads();  // LB visible; H DMA drained

  // segment partials P_s: zero-init scan of rows [32s, 32s+32), 4 segs parallel
  {
    int p = tid & 255, seg = tid >> 8;
    float lre = lam[p], lim = lam[DHID + p];
    float sre = 0.f, sim = 0.f;
    int cb = 4 * p;
#pragma unroll 4
    for (int t = 0; t < 32; ++t) {
      int row = seg * 32 + t;
      unsigned int w = *(const unsigned int*)(H + row * 1024 + (cb ^ ((row & 7) << 4)));
      float bre = f16tof(w), bim = f16tof(w >> 16);
      float nre = fmaf(lre, sre, fmaf(-lim, sim, bre));
      float nim = fmaf(lre, sim, fmaf(lim, sre, bim));
      sre = nre; sim = nim;
    }
    Pp[seg * 512 + 2 * p]     = sre;
    Pp[seg * 512 + 2 * p + 1] = sim;
  }
  __syncthreads();

  // carry combine (bit table) + lambda^32 Horner -> segment start states Tt
  if (tid < 256) {
    int p = tid;
    int lenb = c - (c >> 1);
    float pr = 1.f, pi = 0.f;  // lambda^(128*lenb) via fp64-accurate bit table
#pragma unroll
    for (int j = 0; j < 8; ++j)
      if (lenb & (1 << j)) {
        float br = lam[(4 + 2 * j) * DHID + p], bi = lam[(5 + 2 * j) * DHID + p];
        float nr = pr * br - pi * bi, ni = pr * bi + pi * br;
        pr = nr; pi = ni;
      }
    float sar = LB[2 * p], sai = LB[2 * p + 1];
    float sbr = LB[512 + 2 * p], sbi = LB[512 + 2 * p + 1];
    float tr = fmaf(pr, sar, fmaf(-pi, sai, sbr));   // carry into this chunk
    float ti = fmaf(pr, sai, fmaf(pi, sar, sbi));
    float l32r = lam[2 * DHID + p], l32i = lam[3 * DHID + p];  // lambda^32
    Tt[2 * p] = tr; Tt[2 * p + 1] = ti;
#pragma unroll
    for (int s = 1; s < 4; ++s) {
      float pR = Pp[(s - 1) * 512 + 2 * p], pI = Pp[(s - 1) * 512 + 2 * p + 1];
      float nr = fmaf(l32r, tr, fmaf(-l32i, ti, pR));
      float ni = fmaf(l32r, ti, fmaf(l32i, tr, pI));
      tr = nr; ti = ni;
      Tt[s * 512 + 2 * p] = tr; Tt[s * 512 + 2 * p + 1] = ti;
    }
  }
  __syncthreads();

  // rescan: 4 segments in parallel, in place (fp16 in -> bf16 state out)
  {
    int p = tid & 255, seg = tid >> 8;
    float lre = lam[p], lim = lam[DHID + p];
    float sre = Tt[seg * 512 + 2 * p], sim = Tt[seg * 512 + 2 * p + 1];
    int cb = 4 * p;
#pragma unroll 4
    for (int t = 0; t < 32; ++t) {
      int row = seg * 32 + t;
      unsigned int* ptr = (unsigned int*)(H + row * 1024 + (cb ^ ((row & 7) << 4)));
      unsigned int w = *ptr;
      float bre = f16tof(w), bim = f16tof(w >> 16);
      float nre = fmaf(lre, sre, fmaf(-lim, sim, bre));
      float nim = fmaf(lre, sim, fmaf(lim, sre, bim));
      sre = nre; sim = nim;
      *ptr = (fTobf(sim) << 16) | fTobf(sre);
    }
  }

  // GEMM2: out[128 x 256] = H[128 x 512] @ W2[256 x 512]^T + X*D, 16 waves 4x4
  const int wave = tid >> 6, lane = tid & 63;
  const int wm = wave & 3, wn = wave >> 2;
  const int lrow = lane & 15, lk = lane >> 4;
  f32x4 acc[2][4] = {};
  for (int k0 = 0; k0 < NCH; k0 += 32) {
    __syncthreads();  // first iter: rescan done + LB/Pp dead before Bs overwrite
    async_load16(W2 + (size_t)(tid >> 2) * NCH + k0 + (tid & 3) * 8,
                 (char*)Bs + tid * 16);
    __syncthreads();
    bf16x8 af[2], bfr[4];
#pragma unroll
    for (int i = 0; i < 2; ++i) {
      int m = wm * 32 + i * 16 + lrow;
      af[i] = *(const bf16x8*)(H + m * 1024 + ((2 * k0 + lk * 16) ^ ((m & 7) << 4)));
    }
#pragma unroll
    for (int j = 0; j < 4; ++j)
      bfr[j] = *(const bf16x8*)(Bs + (wn * 64 + j * 16 + lrow) * 32 + lk * 8);
#pragma unroll
    for (int i = 0; i < 2; ++i)
#pragma unroll
      for (int j = 0; j < 4; ++j)
        acc[i][j] = __builtin_amdgcn_mfma_f32_16x16x32_bf16(af[i], bfr[j], acc[i][j], 0, 0, 0);
  }

#pragma unroll
  for (int i = 0; i < 2; ++i)
#pragma unroll
    for (int r = 0; r < 4; ++r) {
      int row = r0 + wm * 32 + i * 16 + lk * 4 + r;
#pragma unroll
      for (int j = 0; j < 4; ++j) {
        int col = wn * 64 + j * 16 + lrow;
        float v = acc[i][j][r] + X[(size_t)row * DMODEL + col] * Dv[col];
        out[(size_t)row * DMODEL + col] = v;
      }
    }
}

extern "C" void kernel_launch(void* const* d_in, const int* in_sizes, int n_in,
                              void* d_out, int out_size, void* d_ws, size_t ws_size,
                              hipStream_t stream) {
  const float* inputs    = (const float*)d_in[0];
  const float* nu_log    = (const float*)d_in[1];
  const float* theta_log = (const float*)d_in[2];
  const float* gamma_log = (const float*)d_in[3];
  const float* B_re      = (const float*)d_in[4];
  const float* B_im      = (const float*)d_in[5];
  const float* C_re      = (const float*)d_in[6];
  const float* C_im      = (const float*)d_in[7];
  const float* Dvec      = (const float*)d_in[8];
  float* out = (float*)d_out;

  char* w = (char*)d_ws;
  bf16_t* W1 = (bf16_t*)w; w += (size_t)NCH * DMODEL * 2;   // 256 KB
  bf16_t* W2 = (bf16_t*)w; w += (size_t)DMODEL * NCH * 2;   // 256 KB
  float* lam = (float*)w;  w += 24576;                      // 20 rows used
  f16_t* Bu  = (f16_t*)w;  w += (size_t)LSEQ * NCH * 2;     // 32 MB
  float* E   = (float*)w;  w += (size_t)NCHUNKS * NCH * 4;  // 512 KB

  // grid: 1 (params) + 512 (W1) + 512 (W2) = 1025
  prep_all<<<1025, 256, 0, stream>>>(nu_log, theta_log, gamma_log,
                                     B_re, B_im, C_re, C_im,
                                     lam, W1, W2);
  gemm1_scan<<<dim3(2, NCHUNKS), 512, 0, stream>>>(inputs, W1, Bu, lam, E);
  scan_gemm2<<<NCHUNKS, 1024, 0, stream>>>(Bu, W2, lam, E, inputs, Dvec, out);
}

// Round 7
// 148.334 us; speedup vs baseline: 1.4952x; 1.0471x over previous
//
#include <hip/hip_runtime.h>
#include <hip/hip_bf16.h>
#include <math.h>

#define LSEQ 32768
#define DMODEL 256
#define DHID 256
#define NCH 512                 // interleaved [re,im] hidden channels: col 2h=re, 2h+1=im
#define CHUNK 128
#define NCHUNKS (LSEQ / CHUNK)  // 256

typedef __bf16 bf16_t;
typedef _Float16 f16_t;
typedef __bf16 bf16x8 __attribute__((ext_vector_type(8)));
typedef float f32x4 __attribute__((ext_vector_type(4)));

__device__ __forceinline__ void async_load16(const void* g, void* l) {
  __builtin_amdgcn_global_load_lds((__attribute__((address_space(1))) void*)g,
                                   (__attribute__((address_space(3))) void*)l,
                                   16, 0, 0);
}

__device__ __forceinline__ float f16tof(unsigned int u) {
  return (float)__builtin_bit_cast(_Float16, (unsigned short)(u & 0xffffu));
}
__device__ __forceinline__ unsigned int fTobf(float f) {
  return (unsigned int)__builtin_bit_cast(unsigned short, (bf16_t)f);
}

// ---- prep: params (10 blocks) + W1 + W2, one launch -------------------------
// lam rows: 0,1 = lambda; 2,3 = lambda^32; 4+2j,5+2j (j=0..7) = lambda^(128*2^j)
__global__ void prep_all(const float* __restrict__ nu_log,
                         const float* __restrict__ theta_log,
                         const float* __restrict__ gamma_log,
                         const float* __restrict__ B_re, const float* __restrict__ B_im,
                         const float* __restrict__ C_re, const float* __restrict__ C_im,
                         float* __restrict__ lam, bf16_t* __restrict__ W1,
                         bf16_t* __restrict__ W2) {
  const int bid = blockIdx.x, tid = threadIdx.x;
  if (bid < 10) {
    int h = tid;
    if (h < DHID) {
      double nu = exp((double)nu_log[h]);
      double th = exp((double)theta_log[h]);
      int row; double n;
      if (bid == 0)      { row = 0; n = 1.0; }
      else if (bid == 1) { row = 2; n = 32.0; }
      else               { row = 4 + 2 * (bid - 2); n = 128.0 * (double)(1 << (bid - 2)); }
      double mag = exp(-n * nu);
      double ph  = fmod(n * th, 6.283185307179586);
      lam[row * DHID + h]       = (float)(mag * cos(ph));
      lam[(row + 1) * DHID + h] = (float)(mag * sin(ph));
    }
  } else if (bid < 522) {
    // W1[n][k], n interleaved: n=2h -> B_re[h][k]*g; n=2h+1 -> B_im[h][k]*g
    int n = bid - 10, k = tid, h = n >> 1;
    float g = expf(gamma_log[h]);
    float v = (((n & 1) == 0) ? B_re[h * DMODEL + k] : B_im[h * DMODEL + k]) * g;
    W1[n * DMODEL + k] = (bf16_t)v;
  } else {
    // W2[m][k], k interleaved: k=2h -> C_re[m][h]; k=2h+1 -> -C_im[m][h]
    int idx = bid - 522;
    int m = idx >> 1, k = (idx & 1) * 256 + tid, h = k >> 1;
    float v = ((k & 1) == 0) ? C_re[m * DHID + h] : -C_im[m * DHID + h];
    W2[m * NCH + k] = (bf16_t)v;
  }
}

// ---------------- kernel A: GEMM1 (chunk tile) + fp16 Bu store + chunk E ----
// grid (2, NCHUNKS), 512 threads, 68 KB LDS, forced 2 blocks/CU.
// 2-phase K-loop: double-buffered As/Bs, stage t+1 before compute t,
// one raw s_barrier + vmcnt/lgkm wait per step (stage latency hides under MFMA).
// Buf b: As at smem + b*24576 (8 KB), Bs at smem + 8192 + b*24576 (16 KB).
__global__ __launch_bounds__(512, 4) void gemm1_scan(
    const float* __restrict__ X, const bf16_t* __restrict__ Bw,
    f16_t* __restrict__ Bu, const float* __restrict__ lam,
    float* __restrict__ E) {
  __shared__ __align__(16) char smem[69632];  // 68 KB
  char*  Bt = smem;                           // [128][512B] fp16 swizzled (epilogue alias)
  float* Ep = (float*)(smem + 65536);         // [4][128][2] f32 = 4 KB

  const int tid = threadIdx.x;
  const int gx = blockIdx.x;          // channel half: pairs [gx*128, gx*128+128)
  const int c  = blockIdx.y;          // chunk
  const int r0 = c * CHUNK;
  const int c0 = gx * 256;            // column offset into the 512-wide Bu
  const int wave = tid >> 6, lane = tid & 63;
  const int wm = wave & 1, wn = wave >> 1;
  const int lrow = lane & 15, lk = lane >> 4;
  const int ra = tid >> 2, ka = (tid & 3) * 8;

  f32x4 acc[4][4] = {};

  // prologue: stage K-step 0 into buf 0
  {
    const float* xrow = X + (size_t)(r0 + ra) * DMODEL + ka;
    float4 a0 = ((const float4*)xrow)[0];
    float4 a1 = ((const float4*)xrow)[1];
    async_load16(Bw + (size_t)(c0 + ra) * DMODEL + ka, smem + 8192 + tid * 16);
    async_load16(Bw + (size_t)(c0 + 128 + ra) * DMODEL + ka, smem + 16384 + tid * 16);
    bf16x8 av = {(bf16_t)a0.x, (bf16_t)a0.y, (bf16_t)a0.z, (bf16_t)a0.w,
                 (bf16_t)a1.x, (bf16_t)a1.y, (bf16_t)a1.z, (bf16_t)a1.w};
    *(bf16x8*)(smem + ra * 64 + ka * 2) = av;
  }
  asm volatile("s_waitcnt vmcnt(0) lgkmcnt(0)" ::: "memory");
  __builtin_amdgcn_s_barrier();

#pragma unroll
  for (int t = 0; t < 8; ++t) {
    const int cur = t & 1, nxt = cur ^ 1;
    const char* Asc = smem + cur * 24576;
    const char* Bsc = smem + 8192 + cur * 24576;
    float4 a0, a1;
    if (t < 7) {  // issue next-step loads (latency spans the MFMAs below)
      const int k0n = (t + 1) * 32;
      const float* xrow = X + (size_t)(r0 + ra) * DMODEL + k0n + ka;
      a0 = ((const float4*)xrow)[0];
      a1 = ((const float4*)xrow)[1];
      async_load16(Bw + (size_t)(c0 + ra) * DMODEL + k0n + ka,
                   smem + 8192 + nxt * 24576 + tid * 16);
      async_load16(Bw + (size_t)(c0 + 128 + ra) * DMODEL + k0n + ka,
                   smem + 16384 + nxt * 24576 + tid * 16);
    }
    bf16x8 af[4], bfr[4];
#pragma unroll
    for (int i = 0; i < 4; ++i)
      af[i] = *(const bf16x8*)(Asc + (wm * 64 + i * 16 + lrow) * 64 + lk * 16);
#pragma unroll
    for (int j = 0; j < 4; ++j)
      bfr[j] = *(const bf16x8*)(Bsc + (wn * 64 + j * 16 + lrow) * 64 + lk * 16);
#pragma unroll
    for (int i = 0; i < 4; ++i)
#pragma unroll
      for (int j = 0; j < 4; ++j)
        acc[i][j] = __builtin_amdgcn_mfma_f32_16x16x32_bf16(af[i], bfr[j], acc[i][j], 0, 0, 0);
    if (t < 7) {  // convert + write A for t+1 (X-load wait lands here, after MFMA)
      bf16x8 av = {(bf16_t)a0.x, (bf16_t)a0.y, (bf16_t)a0.z, (bf16_t)a0.w,
                   (bf16_t)a1.x, (bf16_t)a1.y, (bf16_t)a1.z, (bf16_t)a1.w};
      *(bf16x8*)(smem + nxt * 24576 + ra * 64 + ka * 2) = av;
    }
    asm volatile("s_waitcnt vmcnt(0) lgkmcnt(0)" ::: "memory");
    __builtin_amdgcn_s_barrier();
  }
  // loop ended with a full barrier; staging buffers dead -> Bt may alias

  // acc -> Bt (fp16, swizzled local half-rows of 512B)
#pragma unroll
  for (int i = 0; i < 4; ++i)
#pragma unroll
    for (int r = 0; r < 4; ++r) {
      int row = wm * 64 + i * 16 + lk * 4 + r;
      int key = (row & 7) << 4;
#pragma unroll
      for (int j = 0; j < 4; ++j) {
        int col = wn * 64 + j * 16 + lrow;
        *(f16_t*)(Bt + row * 512 + ((col * 2) ^ key)) = (f16_t)acc[i][j][r];
      }
    }
  __syncthreads();

  // Bt -> global Bu (byte-identical image; (r0+row)&7 == row&7 since r0%128==0)
  char* dst = (char*)Bu + (size_t)r0 * 1024 + gx * 512;
#pragma unroll
  for (int it = 0; it < 8; ++it) {
    int idx = it * 512 + tid;
    int row = idx >> 5, off = (idx & 31) * 16;
    *(f32x4*)(dst + (size_t)row * 1024 + off) = *(const f32x4*)(Bt + row * 512 + off);
  }

  // local end-states: 4 time segments of 32 rows per channel pair
  {
    int p = tid & 127, seg = tid >> 7;
    int h = gx * 128 + p;
    float lre = lam[h], lim = lam[DHID + h];
    float sre = 0.f, sim = 0.f;
    int cb = 4 * p;
#pragma unroll 4
    for (int t = 0; t < 32; ++t) {
      int row = seg * 32 + t;
      unsigned int w = *(const unsigned int*)(Bt + row * 512 + (cb ^ ((row & 7) << 4)));
      float bre = f16tof(w), bim = f16tof(w >> 16);
      float nre = fmaf(lre, sre, fmaf(-lim, sim, bre));
      float nim = fmaf(lre, sim, fmaf(lim, sre, bim));
      sre = nre; sim = nim;
    }
    Ep[seg * 256 + 2 * p]     = sre;
    Ep[seg * 256 + 2 * p + 1] = sim;
  }
  __syncthreads();
  // Horner combine of 4 segments with lambda^32 -> chunk end state E_c
  if (tid < 128) {
    int p = tid, h = gx * 128 + p;
    float ar = lam[2 * DHID + h], ai = lam[3 * DHID + h];  // lambda^32
    float er = Ep[2 * p], ei = Ep[2 * p + 1];
#pragma unroll
    for (int s = 1; s < 4; ++s) {
      float tr = fmaf(ar, er, fmaf(-ai, ei, Ep[s * 256 + 2 * p]));
      float ti = fmaf(ar, ei, fmaf(ai, er, Ep[s * 256 + 2 * p + 1]));
      er = tr; ei = ti;
    }
    E[(size_t)c * NCH + 2 * h]     = er;
    E[(size_t)c * NCH + 2 * h + 1] = ei;
  }
}

// ---------------- kernel B: stage chunk H -> lookback -> parallel scan -> GEMM2
// grid NCHUNKS, 1024 threads, 152 KB LDS. GEMM phase uses T14 reg-staged W2:
// step t+1 loaded to regs during MFMA(t), ds_write between raw barriers
// (no vmcnt(0) drain in the loop). W2 step 0 prefetched at kernel start.
__global__ __launch_bounds__(1024) void scan_gemm2(
    const f16_t* __restrict__ Bu, const bf16_t* __restrict__ W2,
    const float* __restrict__ lam, const float* __restrict__ E,
    const float* __restrict__ X, const float* __restrict__ Dv,
    float* __restrict__ out) {
  __shared__ __align__(16) char smem[155648];
  char*   H  = smem;                          // [128][1024B] swizzled pairs
  bf16_t* Bs = (bf16_t*)(smem + 131072);      // [256][32] 16 KB (GEMM staging)
  float*  LB = (float*)(smem + 131072);       // [2][256][2] 4 KB (aliases Bs, pre-GEMM)
  float*  Pp = (float*)(smem + 135168);       // [4][256][2] 8 KB (aliases Bs, pre-GEMM)
  float*  Tt = (float*)(smem + 147456);       // [4][256][2] 8 KB (no alias)

  const int tid = threadIdx.x;
  const int c = (int)gridDim.x - 1 - (int)blockIdx.x;  // tail-first
  const int r0 = c * CHUNK;

  // issue 128 KB H staging (linear; global image == swizzled LDS image)
  const char* src = (const char*)Bu + (size_t)r0 * 1024;
#pragma unroll
  for (int it = 0; it < 8; ++it)
    async_load16(src + it * 16384 + tid * 16, H + it * 16384 + tid * 16);

  // prefetch W2 step 0 to regs (latency hidden under all scan phases)
  const char* w2src = (const char*)W2 + (size_t)(tid >> 2) * (NCH * 2) + (tid & 3) * 16;
  f32x4 wreg[2];
  wreg[0] = *(const f32x4*)(w2src);

  // lookback partials over E[0..c-1] (threads < 512; overlapped with DMA)
  if (tid < 512) {
    int p = tid & 255, half = tid >> 8;
    int m = c >> 1;
    int lo = half ? m : 0, end = half ? c : m;
    float aR = lam[4 * DHID + p], aI = lam[5 * DHID + p];  // lambda^128
    float sr = 0.f, si = 0.f;
#pragma unroll 4
    for (int k = lo; k < end; ++k) {
      float2 e = *(const float2*)(E + (size_t)k * NCH + 2 * p);
      float nr = fmaf(aR, sr, fmaf(-aI, si, e.x));
      float ni = fmaf(aR, si, fmaf(aI, sr, e.y));
      sr = nr; si = ni;
    }
    LB[half * 512 + 2 * p]     = sr;
    LB[half * 512 + 2 * p + 1] = si;
  }
  __syncthreads();  // LB visible; H DMA drained

  // segment partials P_s: zero-init scan of rows [32s, 32s+32), 4 segs parallel
  {
    int p = tid & 255, seg = tid >> 8;
    float lre = lam[p], lim = lam[DHID + p];
    float sre = 0.f, sim = 0.f;
    int cb = 4 * p;
#pragma unroll 4
    for (int t = 0; t < 32; ++t) {
      int row = seg * 32 + t;
      unsigned int w = *(const unsigned int*)(H + row * 1024 + (cb ^ ((row & 7) << 4)));
      float bre = f16tof(w), bim = f16tof(w >> 16);
      float nre = fmaf(lre, sre, fmaf(-lim, sim, bre));
      float nim = fmaf(lre, sim, fmaf(lim, sre, bim));
      sre = nre; sim = nim;
    }
    Pp[seg * 512 + 2 * p]     = sre;
    Pp[seg * 512 + 2 * p + 1] = sim;
  }
  __syncthreads();

  // carry combine (bit table) + lambda^32 Horner -> segment start states Tt
  if (tid < 256) {
    int p = tid;
    int lenb = c - (c >> 1);
    float pr = 1.f, pi = 0.f;  // lambda^(128*lenb) via fp64-accurate bit table
#pragma unroll
    for (int j = 0; j < 8; ++j)
      if (lenb & (1 << j)) {
        float br = lam[(4 + 2 * j) * DHID + p], bi = lam[(5 + 2 * j) * DHID + p];
        float nr = pr * br - pi * bi, ni = pr * bi + pi * br;
        pr = nr; pi = ni;
      }
    float sar = LB[2 * p], sai = LB[2 * p + 1];
    float sbr = LB[512 + 2 * p], sbi = LB[512 + 2 * p + 1];
    float tr = fmaf(pr, sar, fmaf(-pi, sai, sbr));   // carry into this chunk
    float ti = fmaf(pr, sai, fmaf(pi, sar, sbi));
    float l32r = lam[2 * DHID + p], l32i = lam[3 * DHID + p];  // lambda^32
    Tt[2 * p] = tr; Tt[2 * p + 1] = ti;
#pragma unroll
    for (int s = 1; s < 4; ++s) {
      float pR = Pp[(s - 1) * 512 + 2 * p], pI = Pp[(s - 1) * 512 + 2 * p + 1];
      float nr = fmaf(l32r, tr, fmaf(-l32i, ti, pR));
      float ni = fmaf(l32r, ti, fmaf(l32i, tr, pI));
      tr = nr; ti = ni;
      Tt[s * 512 + 2 * p] = tr; Tt[s * 512 + 2 * p + 1] = ti;
    }
  }
  __syncthreads();

  // rescan: 4 segments in parallel, in place (fp16 in -> bf16 state out)
  {
    int p = tid & 255, seg = tid >> 8;
    float lre = lam[p], lim = lam[DHID + p];
    float sre = Tt[seg * 512 + 2 * p], sim = Tt[seg * 512 + 2 * p + 1];
    int cb = 4 * p;
#pragma unroll 4
    for (int t = 0; t < 32; ++t) {
      int row = seg * 32 + t;
      unsigned int* ptr = (unsigned int*)(H + row * 1024 + (cb ^ ((row & 7) << 4)));
      unsigned int w = *ptr;
      float bre = f16tof(w), bim = f16tof(w >> 16);
      float nre = fmaf(lre, sre, fmaf(-lim, sim, bre));
      float nim = fmaf(lre, sim, fmaf(lim, sre, bim));
      sre = nre; sim = nim;
      *ptr = (fTobf(sim) << 16) | fTobf(sre);
    }
  }
  __syncthreads();  // rescan done; LB/Pp dead -> Bs region free

  // GEMM2: out[128 x 256] = H[128 x 512] @ W2[256 x 512]^T + X*D, 16 waves 4x4
  const int wave = tid >> 6, lane = tid & 63;
  const int wm = wave & 3, wn = wave >> 2;
  const int lrow = lane & 15, lk = lane >> 4;
  *(f32x4*)((char*)Bs + tid * 16) = wreg[0];     // step 0 into LDS
  wreg[1] = *(const f32x4*)(w2src + 64);         // prefetch step 1
  asm volatile("s_waitcnt lgkmcnt(0)" ::: "memory");
  __builtin_amdgcn_s_barrier();

  f32x4 acc[2][4] = {};
#pragma unroll
  for (int t = 0; t < 16; ++t) {
    const int k0 = t * 32;
    bf16x8 af[2], bfr[4];
#pragma unroll
    for (int i = 0; i < 2; ++i) {
      int m = wm * 32 + i * 16 + lrow;
      af[i] = *(const bf16x8*)(H + m * 1024 + ((2 * k0 + lk * 16) ^ ((m & 7) << 4)));
    }
#pragma unroll
    for (int j = 0; j < 4; ++j)
      bfr[j] = *(const bf16x8*)(Bs + (wn * 64 + j * 16 + lrow) * 32 + lk * 8);
#pragma unroll
    for (int i = 0; i < 2; ++i)
#pragma unroll
      for (int j = 0; j < 4; ++j)
        acc[i][j] = __builtin_amdgcn_mfma_f32_16x16x32_bf16(af[i], bfr[j], acc[i][j], 0, 0, 0);
    if (t < 15) {
      __builtin_amdgcn_s_barrier();              // all waves done reading step t
      *(f32x4*)((char*)Bs + tid * 16) = wreg[(t + 1) & 1];
      if (t < 14) wreg[t & 1] = *(const f32x4*)(w2src + 64 * (t + 2));
      asm volatile("s_waitcnt lgkmcnt(0)" ::: "memory");
      __builtin_amdgcn_s_barrier();              // step t+1 visible
    }
  }

#pragma unroll
  for (int i = 0; i < 2; ++i)
#pragma unroll
    for (int r = 0; r < 4; ++r) {
      int row = r0 + wm * 32 + i * 16 + lk * 4 + r;
#pragma unroll
      for (int j = 0; j < 4; ++j) {
        int col = wn * 64 + j * 16 + lrow;
        float v = acc[i][j][r] + X[(size_t)row * DMODEL + col] * Dv[col];
        out[(size_t)row * DMODEL + col] = v;
      }
    }
}

extern "C" void kernel_launch(void* const* d_in, const int* in_sizes, int n_in,
                              void* d_out, int out_size, void* d_ws, size_t ws_size,
                              hipStream_t stream) {
  const float* inputs    = (const float*)d_in[0];
  const float* nu_log    = (const float*)d_in[1];
  const float* theta_log = (const float*)d_in[2];
  const float* gamma_log = (const float*)d_in[3];
  const float* B_re      = (const float*)d_in[4];
  const float* B_im      = (const float*)d_in[5];
  const float* C_re      = (const float*)d_in[6];
  const float* C_im      = (const float*)d_in[7];
  const float* Dvec      = (const float*)d_in[8];
  float* out = (float*)d_out;

  char* w = (char*)d_ws;
  bf16_t* W1 = (bf16_t*)w; w += (size_t)NCH * DMODEL * 2;   // 256 KB
  bf16_t* W2 = (bf16_t*)w; w += (size_t)DMODEL * NCH * 2;   // 256 KB
  float* lam = (float*)w;  w += 24576;                      // 20 rows used
  f16_t* Bu  = (f16_t*)w;  w += (size_t)LSEQ * NCH * 2;     // 32 MB
  float* E   = (float*)w;  w += (size_t)NCHUNKS * NCH * 4;  // 512 KB

  // grid: 10 (params) + 512 (W1) + 512 (W2) = 1034
  prep_all<<<1034, 256, 0, stream>>>(nu_log, theta_log, gamma_log,
                                     B_re, B_im, C_re, C_im,
                                     lam, W1, W2);
  gemm1_scan<<<dim3(2, NCHUNKS), 512, 0, stream>>>(inputs, W1, Bu, lam, E);
  scan_gemm2<<<NCHUNKS, 1024, 0, stream>>>(Bu, W2, lam, E, inputs, Dvec, out);
}